// Round 2
// baseline (5892.408 us; speedup 1.0000x reference)
//
#include <hip/hip_runtime.h>
#include <stdint.h>

#define B_    4096
#define D_    768
#define FUP   12288
#define FDN   12288
#define CONN  256
#define KTOP  64
#define CHUNK 1024
#define NCH   (B_ / CHUNK)

// ---------------------------------------------------------------- utilities

__device__ __forceinline__ unsigned fkey(float x) {
    unsigned u = __float_as_uint(x);
    return (u & 0x80000000u) ? ~u : (u | 0x80000000u);
}

// Block-wide top-64 select over vals[0..n) (LDS resident), exact jax
// tie-breaking (lowest index among equals at the threshold).
// scratch: [0]=need, [1]=prefix/thresh, [2]=cnt_greater, [3]=eqcnt, [4..67]=eq idx
__device__ void topk64_block(const float* vals, int n, int* gidx, float* gval,
                             unsigned* hist, int* scratch)
{
    const int tid = threadIdx.x;
    if (tid == 0) { scratch[0] = KTOP; scratch[1] = 0; scratch[2] = 0; scratch[3] = 0; }
    for (int l = 24; l >= 0; l -= 8) {
        hist[tid] = 0;
        __syncthreads();
        unsigned prefix = (unsigned)scratch[1];
        unsigned hm = (l == 24) ? 0u : (0xFFFFFFFFu << (l + 8));
        for (int i = tid; i < n; i += 256) {
            unsigned key = fkey(vals[i]);
            if ((key & hm) == (prefix & hm)) atomicAdd(&hist[(key >> l) & 255], 1u);
        }
        __syncthreads();
        if (tid == 0) {
            int need = scratch[0];
            unsigned acc = 0;
            for (int b2 = 255; b2 >= 0; --b2) {
                unsigned h = hist[b2];
                if (acc + h >= (unsigned)need) {
                    scratch[1] = (int)(prefix | ((unsigned)b2 << l));
                    scratch[0] = need - (int)acc;
                    break;
                }
                acc += h;
            }
        }
        __syncthreads();
    }
    unsigned thresh = (unsigned)scratch[1];
    for (int i = tid; i < n; i += 256) {
        float v = vals[i];
        unsigned key = fkey(v);
        if (key > thresh) {
            int p = atomicAdd(&scratch[2], 1);
            gidx[p] = i; gval[p] = v;
        } else if (key == thresh) {
            int p = atomicAdd(&scratch[3], 1);
            if (p < 64) scratch[4 + p] = i;
        }
    }
    __syncthreads();
    if (tid == 0) {
        int cnt = scratch[2];
        int ne  = KTOP - cnt;
        int ec  = scratch[3] < 64 ? scratch[3] : 64;
        for (int a2 = 0; a2 < ne; ++a2) {
            int best = 0x7fffffff, bi = -1;
            for (int q = 0; q < ec; ++q) {
                int id = scratch[4 + q];
                if (id >= 0 && id < best) { best = id; bi = q; }
            }
            if (bi >= 0) {
                scratch[4 + bi] = -1;
                gidx[cnt + a2] = best; gval[cnt + a2] = vals[best];
            }
        }
    }
    __syncthreads();
}

// ---------------------------------------------------------------- kernels

// detect int64-vs-int32 connections: int64 little-endian => odd words all 0
__global__ void k_detect(const int* __restrict__ conn, int* mode) {
    if (blockIdx.x == 0 && threadIdx.x == 0) {
        int z = 1;
        for (int i = 1; i < 128; i += 2) z &= (conn[i] == 0);
        *mode = z;
    }
}

__device__ __forceinline__ int getconn(const int* c, size_t e, int mode) {
    return mode ? c[2 * e] : c[e];
}

__global__ void k_zero(unsigned* __restrict__ p, int n) {
    for (int i = blockIdx.x * blockDim.x + threadIdx.x; i < n;
         i += gridDim.x * blockDim.x)
        p[i] = 0u;
}

// in[R][Cc] -> out[Cc][R]
__global__ void k_transpose(const float* __restrict__ in, float* __restrict__ out,
                            int R, int Cc) {
    __shared__ float t[32][33];
    int x = blockIdx.x * 32 + threadIdx.x;
    int yb = blockIdx.y * 32;
    for (int j = threadIdx.y; j < 32; j += 8)
        t[j][threadIdx.x] = in[(size_t)(yb + j) * Cc + x];
    __syncthreads();
    int xo  = yb + threadIdx.x;
    int yb2 = blockIdx.x * 32;
    for (int j = threadIdx.y; j < 32; j += 8)
        out[(size_t)(yb2 + j) * R + xo] = t[threadIdx.x][j];
}

// bias_up[f] = b_enc_up[f] - W_enc_up[f]·b_dec_up
// c_in[f]    = W_enc_down[f]·b_dec_up          (inside ln scale)
// c_out[f]   = b_enc_down[f] - W_enc_down[f]·b_dec_down  (outside ln scale)
__global__ void k_precompute(const float* __restrict__ Wup, const float* __restrict__ Wdn,
                             const float* __restrict__ b_enc_up, const float* __restrict__ b_enc_down,
                             const float* __restrict__ b_dec_up, const float* __restrict__ b_dec_down,
                             float* __restrict__ bias_up, float* __restrict__ c_in,
                             float* __restrict__ c_out) {
    int wave = threadIdx.x >> 6, lane = threadIdx.x & 63;
    int f = blockIdx.x * 4 + wave;
    if (f >= FUP) return;
    const float* ru = Wup + (size_t)f * D_;
    const float* rd = Wdn + (size_t)f * D_;
    float s1 = 0.f, s2 = 0.f, s3 = 0.f;
    for (int d = lane; d < D_; d += 64) {
        float bu = b_dec_up[d], bd = b_dec_down[d];
        s1 += ru[d] * bu;
        float w = rd[d];
        s2 += w * bu;
        s3 += w * bd;
    }
    for (int m = 32; m; m >>= 1) {
        s1 += __shfl_xor(s1, m);
        s2 += __shfl_xor(s2, m);
        s3 += __shfl_xor(s3, m);
    }
    if (!lane) {
        bias_up[f] = b_enc_up[f] - s1;
        c_in[f]  = s2;
        c_out[f] = b_enc_down[f] - s3;
    }
}

// C[M,N] = A[M,K] @ B[N,K]^T (+bias) (+relu).  128x128 tile, 8x8 microtile.
#define BM 128
#define BN 128
#define BK 16
__global__ __launch_bounds__(256) void k_gemm_nt(
    const float* __restrict__ A, const float* __restrict__ Bm,
    float* __restrict__ C, const float* __restrict__ bias,
    int M, int N, int K, int doRelu)
{
    __shared__ __attribute__((aligned(16))) float As[BK][BM + 4];
    __shared__ __attribute__((aligned(16))) float Bs[BK][BN + 4];
    const int tid = threadIdx.x;
    const int tx = tid & 15, ty = tid >> 4;
    const int bm = blockIdx.y * BM, bn = blockIdx.x * BN;
    const int lr = tid >> 2, lc = (tid & 3) << 2;
    const float* Aptr = A + (size_t)(bm + lr) * K + lc;
    const float* Bptr = Bm + (size_t)(bn + lr) * K + lc;
    float acc[8][8] = {};
    for (int k0 = 0; k0 < K; k0 += BK) {
        float4 a0 = *(const float4*)(Aptr + k0);
        float4 a1 = *(const float4*)(Aptr + (size_t)64 * K + k0);
        float4 b0 = *(const float4*)(Bptr + k0);
        float4 b1 = *(const float4*)(Bptr + (size_t)64 * K + k0);
        __syncthreads();
        As[lc + 0][lr] = a0.x; As[lc + 1][lr] = a0.y; As[lc + 2][lr] = a0.z; As[lc + 3][lr] = a0.w;
        As[lc + 0][lr + 64] = a1.x; As[lc + 1][lr + 64] = a1.y; As[lc + 2][lr + 64] = a1.z; As[lc + 3][lr + 64] = a1.w;
        Bs[lc + 0][lr] = b0.x; Bs[lc + 1][lr] = b0.y; Bs[lc + 2][lr] = b0.z; Bs[lc + 3][lr] = b0.w;
        Bs[lc + 0][lr + 64] = b1.x; Bs[lc + 1][lr + 64] = b1.y; Bs[lc + 2][lr + 64] = b1.z; Bs[lc + 3][lr + 64] = b1.w;
        __syncthreads();
#pragma unroll
        for (int kk = 0; kk < BK; ++kk) {
            float a[8], bv[8];
            *(float4*)&a[0]  = *(const float4*)&As[kk][ty * 8];
            *(float4*)&a[4]  = *(const float4*)&As[kk][ty * 8 + 4];
            *(float4*)&bv[0] = *(const float4*)&Bs[kk][tx * 8];
            *(float4*)&bv[4] = *(const float4*)&Bs[kk][tx * 8 + 4];
#pragma unroll
            for (int i = 0; i < 8; ++i)
#pragma unroll
                for (int j = 0; j < 8; ++j)
                    acc[i][j] = fmaf(a[i], bv[j], acc[i][j]);
        }
    }
    float bloc[8];
#pragma unroll
    for (int j = 0; j < 8; ++j) bloc[j] = bias ? bias[bn + tx * 8 + j] : 0.f;
#pragma unroll
    for (int i = 0; i < 8; ++i) {
        int m = bm + ty * 8 + i;
        float* crow = C + (size_t)m * N + bn + tx * 8;
        float v[8];
#pragma unroll
        for (int j = 0; j < 8; ++j) {
            float t = acc[i][j] + bloc[j];
            v[j] = doRelu ? fmaxf(t, 0.f) : t;
        }
        *(float4*)(crow)     = make_float4(v[0], v[1], v[2], v[3]);
        *(float4*)(crow + 4) = make_float4(v[4], v[5], v[6], v[7]);
    }
}

__global__ __launch_bounds__(256) void k_topk_up(const float* __restrict__ big,
                                                 int* __restrict__ up_idx,
                                                 float* __restrict__ up_val) {
    __shared__ __attribute__((aligned(16))) float row[FUP];
    __shared__ unsigned hist[256];
    __shared__ int scratch[68];
    int b = blockIdx.x;
    const float4* s4 = (const float4*)(big + (size_t)b * FUP);
    float4* r4 = (float4*)row;
    for (int i = threadIdx.x; i < FUP / 4; i += 256) r4[i] = s4[i];
    __syncthreads();
    topk64_block(row, FUP, up_idx + b * 64, up_val + b * 64, hist, scratch);
}

// pd[fd,c] = W_enc_down[fd]·W_dec_upT[conn[fd,c]]  (0 on duplicate conn)
__global__ __launch_bounds__(256) void k_pd(const float* __restrict__ Wdn,
                                            const float* __restrict__ WduT,
                                            const int* __restrict__ conn,
                                            const int* __restrict__ mode_p,
                                            float* __restrict__ pd) {
    __shared__ float wrow[D_];
    __shared__ int crow[CONN];
    int fd = blockIdx.x;
    int mode = *mode_p;
    const float* wsrc = Wdn + (size_t)fd * D_;
    for (int i = threadIdx.x; i < D_; i += 256) wrow[i] = wsrc[i];
    for (int i = threadIdx.x; i < CONN; i += 256)
        crow[i] = getconn(conn, (size_t)fd * CONN + i, mode);
    __syncthreads();
    int wave = threadIdx.x >> 6, lane = threadIdx.x & 63;
    for (int c = wave; c < CONN; c += 4) {
        int fu = crow[c];
        bool dup = false;
        for (int q = lane; q < c; q += 64) dup |= (crow[q] == fu);
        unsigned long long anyDup = __ballot(dup);
        const float* wu = WduT + (size_t)fu * D_;
        float s = 0.f;
        for (int d = lane; d < D_; d += 64) s += wrow[d] * wu[d];
        for (int m = 32; m; m >>= 1) s += __shfl_xor(s, m);
        if (!lane) pd[(size_t)fd * CONN + c] = anyDup ? 0.f : s;
    }
}

__global__ void k_hist(const int* __restrict__ conn, const int* __restrict__ mode_p,
                       unsigned* __restrict__ counts, int total) {
    int mode = *mode_p;
    for (int e = blockIdx.x * blockDim.x + threadIdx.x; e < total;
         e += gridDim.x * blockDim.x)
        atomicAdd(&counts[getconn(conn, (size_t)e, mode)], 1u);
}

__global__ void k_scan(const unsigned* __restrict__ counts,
                       unsigned* __restrict__ offsets, unsigned* __restrict__ cursor) {
    __shared__ unsigned sums[256];
    int tid = threadIdx.x;
    const int CH = FUP / 256;   // 48
    unsigned local = 0;
    for (int i = 0; i < CH; ++i) local += counts[tid * CH + i];
    sums[tid] = local;
    __syncthreads();
    for (int off = 1; off < 256; off <<= 1) {
        unsigned v = 0;
        if (tid >= off) v = sums[tid - off];
        __syncthreads();
        sums[tid] += v;
        __syncthreads();
    }
    unsigned run = (tid == 0) ? 0u : sums[tid - 1];
    for (int i = 0; i < CH; ++i) {
        int idx = tid * CH + i;
        offsets[idx] = run;
        cursor[idx]  = run;
        run += counts[idx];
    }
    if (tid == 255) offsets[FUP] = run;
}

__global__ void k_scatter(const int* __restrict__ conn, const int* __restrict__ mode_p,
                          const float* __restrict__ pd, unsigned* __restrict__ cursor,
                          unsigned short* __restrict__ rev_fd, float* __restrict__ rev_w,
                          int total) {
    int mode = *mode_p;
    for (int e = blockIdx.x * blockDim.x + threadIdx.x; e < total;
         e += gridDim.x * blockDim.x) {
        int fu = getconn(conn, (size_t)e, mode);
        unsigned pos = atomicAdd(&cursor[fu], 1u);
        rev_fd[pos] = (unsigned short)(e >> 8);   // fd = e / CONN
        rev_w[pos]  = pd[e];
    }
}

// per-batch-row: contributions scatter + combine + top-64 of approx
__global__ __launch_bounds__(256) void k_down(
    const float* __restrict__ big /*approx0*/, const float* __restrict__ ln_scale,
    const float* __restrict__ c_in, const float* __restrict__ c_out,
    const int* __restrict__ up_idx, const float* __restrict__ up_val,
    const unsigned* __restrict__ offsets, const unsigned short* __restrict__ rev_fd,
    const float* __restrict__ rev_w, int* __restrict__ down_idx,
    float* __restrict__ down_val)
{
    __shared__ __attribute__((aligned(16))) float contrib[FDN];
    __shared__ unsigned hist[256];
    __shared__ int scratch[68];
    int b = blockIdx.x, tid = threadIdx.x;
    float4* c4 = (float4*)contrib;
    for (int i = tid; i < FDN / 4; i += 256) c4[i] = make_float4(0.f, 0.f, 0.f, 0.f);
    __syncthreads();
    for (int j = 0; j < KTOP; ++j) {
        int fu = up_idx[b * 64 + j];
        float v = up_val[b * 64 + j];
        unsigned s = offsets[fu], e = offsets[fu + 1];
        for (unsigned t = s + tid; t < e; t += 256)
            atomicAdd(&contrib[rev_fd[t]], v * rev_w[t]);
    }
    __syncthreads();
    float ls = ln_scale[b];
    const float* ap = big + (size_t)b * FDN;
    for (int i = tid; i < FDN; i += 256)
        contrib[i] = (ap[i] + contrib[i] + c_in[i]) / ls + c_out[i];
    __syncthreads();
    topk64_block(contrib, FDN, down_idx + b * 64, down_val + b * 64, hist, scratch);
}

__global__ __launch_bounds__(256) void k_decode(
    const int* __restrict__ down_idx, const float* __restrict__ down_val,
    const float* __restrict__ WddT, const float* __restrict__ b_dec_down,
    float* __restrict__ out)
{
    __shared__ int fidx[64];
    __shared__ float fval[64];
    int b = blockIdx.x, tid = threadIdx.x;
    if (tid < 64) { fidx[tid] = down_idx[b * 64 + tid]; fval[tid] = down_val[b * 64 + tid]; }
    __syncthreads();
    float a0 = b_dec_down[tid], a1 = b_dec_down[tid + 256], a2 = b_dec_down[tid + 512];
    for (int j = 0; j < 64; ++j) {
        const float* r = WddT + (size_t)fidx[j] * D_;
        float v = fval[j];
        a0 += v * r[tid];
        a1 += v * r[tid + 256];
        a2 += v * r[tid + 512];
    }
    float* o = out + (size_t)b * D_;
    o[tid] = a0; o[tid + 256] = a1; o[tid + 512] = a2;
}

// ---------------------------------------------------------------- launch

extern "C" void kernel_launch(void* const* d_in, const int* in_sizes, int n_in,
                              void* d_out, int out_size, void* d_ws, size_t ws_size,
                              hipStream_t stream)
{
    const float* initial_acts = (const float*)d_in[0];
    const float* x_up         = (const float*)d_in[1];
    const float* ln_scale     = (const float*)d_in[2];
    const float* W_enc_up     = (const float*)d_in[3];
    const float* b_enc_up     = (const float*)d_in[4];
    const float* b_dec_up     = (const float*)d_in[5];
    const float* W_dec_up     = (const float*)d_in[6];
    const float* W_enc_down   = (const float*)d_in[7];
    const float* b_enc_down   = (const float*)d_in[8];
    const float* b_dec_down   = (const float*)d_in[9];
    const float* W_dec_down   = (const float*)d_in[10];
    const int*   conn         = (const int*)d_in[11];
    float* out = (float*)d_out;

    // ---- workspace layout (total ~111.5 MB; chunked big keeps us far
    //      under any plausible ws_size; round-1 layout was 268.8 MB and
    //      aborted — suspected 256 MiB ws overflow) ----
    char* w = (char*)d_ws;
    float*          big      = (float*)(w);                 // 50,331,648 B (CHUNK x FUP)
    float*          pd       = big;                         // overlap: dead before GEMM2 chunks
    float*          Wt       = (float*)(w + 50331648);      // 37,748,736 B (WduT then WddT)
    float*          rev_w    = (float*)(w + 88080384);      // 12,582,912 B
    unsigned short* rev_fd   = (unsigned short*)(w + 100663296); // 6,291,456 B
    int*            up_idx   = (int*)  (w + 106954752);     // 1 MiB
    float*          up_val   = (float*)(w + 108003328);     // 1 MiB
    int*            down_idx = (int*)  (w + 109051904);     // 1 MiB
    float*          down_val = (float*)(w + 110100480);     // 1 MiB
    unsigned*       offsets  = (unsigned*)(w + 111149056);  // 64 KiB (12289 used)
    unsigned*       cursor   = (unsigned*)(w + 111214592);  // 64 KiB
    unsigned*       counts   = (unsigned*)(w + 111280128);  // 64 KiB
    float*          bias_up  = (float*)(w + 111345664);     // 48 KiB
    float*          c_in     = (float*)(w + 111394816);     // 48 KiB
    float*          c_out    = (float*)(w + 111443968);     // 48 KiB
    int*            mode_p   = (int*)  (w + 111493120);

    const int total_conn = FDN * CONN;
    dim3 tb(32, 8);

    k_detect<<<1, 64, 0, stream>>>(conn, mode_p);
    k_transpose<<<dim3(FUP / 32, D_ / 32), tb, 0, stream>>>(W_dec_up, Wt, D_, FUP);
    k_precompute<<<FUP / 4, 256, 0, stream>>>(W_enc_up, W_enc_down, b_enc_up, b_enc_down,
                                              b_dec_up, b_dec_down, bias_up, c_in, c_out);
    // phase 1: pre_up = relu(x_up @ W_enc_up^T + bias_up), then top-64, per chunk
    for (int c = 0; c < NCH; ++c) {
        k_gemm_nt<<<dim3(FUP / BN, CHUNK / BM), 256, 0, stream>>>(
            x_up + (size_t)c * CHUNK * D_, W_enc_up, big, bias_up, CHUNK, FUP, D_, 1);
        k_topk_up<<<CHUNK, 256, 0, stream>>>(big, up_idx + (size_t)c * CHUNK * 64,
                                             up_val + (size_t)c * CHUNK * 64);
    }
    // pair dots into pd (overlaps big; pre_up chunks are dead)
    k_pd<<<FDN, 256, 0, stream>>>(W_enc_down, Wt, conn, mode_p, pd);
    k_zero<<<48, 256, 0, stream>>>(counts, FUP);
    k_hist<<<4096, 256, 0, stream>>>(conn, mode_p, counts, total_conn);
    k_scan<<<1, 256, 0, stream>>>(counts, offsets, cursor);
    k_scatter<<<4096, 256, 0, stream>>>(conn, mode_p, pd, cursor, rev_fd, rev_w, total_conn);
    // WddT (WduT dead after k_pd)
    k_transpose<<<dim3(FDN / 32, D_ / 32), tb, 0, stream>>>(W_dec_down, Wt, D_, FDN);
    // phase 2: approx0 = initial_acts @ W_enc_down^T, combine + top-64, per chunk
    for (int c = 0; c < NCH; ++c) {
        k_gemm_nt<<<dim3(FDN / BN, CHUNK / BM), 256, 0, stream>>>(
            initial_acts + (size_t)c * CHUNK * D_, W_enc_down, big, nullptr,
            CHUNK, FDN, D_, 0);
        k_down<<<CHUNK, 256, 0, stream>>>(big, ln_scale + (size_t)c * CHUNK, c_in, c_out,
                                          up_idx + (size_t)c * CHUNK * 64,
                                          up_val + (size_t)c * CHUNK * 64,
                                          offsets, rev_fd, rev_w,
                                          down_idx + (size_t)c * CHUNK * 64,
                                          down_val + (size_t)c * CHUNK * 64);
    }
    k_decode<<<B_, 256, 0, stream>>>(down_idx, down_val, Wt, b_dec_down, out);
}

// Round 3
// 5792.783 us; speedup vs baseline: 1.0172x; 1.0172x over previous
//
#include <hip/hip_runtime.h>
#include <stdint.h>

#define B_    4096
#define D_    768
#define FUP   12288
#define FDN   12288
#define CONN  256
#define KTOP  64
#define CHUNK 1024
#define NCH   (B_ / CHUNK)
#define PDW   1024            // k_pd fu-window (3 MB fp32: fits 4 MB per-XCD L2)
#define NPW   (FUP / PDW)     // 12 windows

// ---------------------------------------------------------------- utilities

__device__ __forceinline__ unsigned fkey(float x) {
    unsigned u = __float_as_uint(x);
    return (u & 0x80000000u) ? ~u : (u | 0x80000000u);
}

// Block-wide top-64 select over vals[0..n) (LDS resident), exact jax
// tie-breaking (lowest index among equals at the threshold).
__device__ void topk64_block(const float* vals, int n, int* gidx, float* gval,
                             unsigned* hist, int* scratch)
{
    const int tid = threadIdx.x;
    if (tid == 0) { scratch[0] = KTOP; scratch[1] = 0; scratch[2] = 0; scratch[3] = 0; }
    for (int l = 24; l >= 0; l -= 8) {
        hist[tid] = 0;
        __syncthreads();
        unsigned prefix = (unsigned)scratch[1];
        unsigned hm = (l == 24) ? 0u : (0xFFFFFFFFu << (l + 8));
        for (int i = tid; i < n; i += 256) {
            unsigned key = fkey(vals[i]);
            if ((key & hm) == (prefix & hm)) atomicAdd(&hist[(key >> l) & 255], 1u);
        }
        __syncthreads();
        if (tid == 0) {
            int need = scratch[0];
            unsigned acc = 0;
            for (int b2 = 255; b2 >= 0; --b2) {
                unsigned h = hist[b2];
                if (acc + h >= (unsigned)need) {
                    scratch[1] = (int)(prefix | ((unsigned)b2 << l));
                    scratch[0] = need - (int)acc;
                    break;
                }
                acc += h;
            }
        }
        __syncthreads();
    }
    unsigned thresh = (unsigned)scratch[1];
    for (int i = tid; i < n; i += 256) {
        float v = vals[i];
        unsigned key = fkey(v);
        if (key > thresh) {
            int p = atomicAdd(&scratch[2], 1);
            gidx[p] = i; gval[p] = v;
        } else if (key == thresh) {
            int p = atomicAdd(&scratch[3], 1);
            if (p < 64) scratch[4 + p] = i;
        }
    }
    __syncthreads();
    if (tid == 0) {
        int cnt = scratch[2];
        int ne  = KTOP - cnt;
        int ec  = scratch[3] < 64 ? scratch[3] : 64;
        for (int a2 = 0; a2 < ne; ++a2) {
            int best = 0x7fffffff, bi = -1;
            for (int q = 0; q < ec; ++q) {
                int id = scratch[4 + q];
                if (id >= 0 && id < best) { best = id; bi = q; }
            }
            if (bi >= 0) {
                scratch[4 + bi] = -1;
                gidx[cnt + a2] = best; gval[cnt + a2] = vals[best];
            }
        }
    }
    __syncthreads();
}

// ---------------------------------------------------------------- kernels

__global__ void k_detect(const int* __restrict__ conn, int* mode) {
    if (blockIdx.x == 0 && threadIdx.x == 0) {
        int z = 1;
        for (int i = 1; i < 128; i += 2) z &= (conn[i] == 0);
        *mode = z;
    }
}

__device__ __forceinline__ int getconn(const int* c, size_t e, int mode) {
    return mode ? c[2 * e] : c[e];
}

__global__ void k_zero(unsigned* __restrict__ p, int n) {
    for (int i = blockIdx.x * blockDim.x + threadIdx.x; i < n;
         i += gridDim.x * blockDim.x)
        p[i] = 0u;
}

// in[R][Cc] -> out[Cc][R]
__global__ void k_transpose(const float* __restrict__ in, float* __restrict__ out,
                            int R, int Cc) {
    __shared__ float t[32][33];
    int x = blockIdx.x * 32 + threadIdx.x;
    int yb = blockIdx.y * 32;
    for (int j = threadIdx.y; j < 32; j += 8)
        t[j][threadIdx.x] = in[(size_t)(yb + j) * Cc + x];
    __syncthreads();
    int xo  = yb + threadIdx.x;
    int yb2 = blockIdx.x * 32;
    for (int j = threadIdx.y; j < 32; j += 8)
        out[(size_t)(yb2 + j) * R + xo] = t[threadIdx.x][j];
}

__global__ void k_precompute(const float* __restrict__ Wup, const float* __restrict__ Wdn,
                             const float* __restrict__ b_enc_up, const float* __restrict__ b_enc_down,
                             const float* __restrict__ b_dec_up, const float* __restrict__ b_dec_down,
                             float* __restrict__ bias_up, float* __restrict__ c_in,
                             float* __restrict__ c_out) {
    int wave = threadIdx.x >> 6, lane = threadIdx.x & 63;
    int f = blockIdx.x * 4 + wave;
    if (f >= FUP) return;
    const float* ru = Wup + (size_t)f * D_;
    const float* rd = Wdn + (size_t)f * D_;
    float s1 = 0.f, s2 = 0.f, s3 = 0.f;
    for (int d = lane; d < D_; d += 64) {
        float bu = b_dec_up[d], bd = b_dec_down[d];
        s1 += ru[d] * bu;
        float w = rd[d];
        s2 += w * bu;
        s3 += w * bd;
    }
    for (int m = 32; m; m >>= 1) {
        s1 += __shfl_xor(s1, m);
        s2 += __shfl_xor(s2, m);
        s3 += __shfl_xor(s3, m);
    }
    if (!lane) {
        bias_up[f] = b_enc_up[f] - s1;
        c_in[f]  = s2;
        c_out[f] = b_enc_down[f] - s3;
    }
}

// C[M,N] = A[M,K] @ B[N,K]^T (+bias) (+relu).  128x128 tile, 8x8 microtile,
// BK=32 (k-accumulation order identical to BK=16 version -> bit-identical).
#define BM 128
#define BN 128
#define BK 32
__global__ __launch_bounds__(256, 2) void k_gemm_nt(
    const float* __restrict__ A, const float* __restrict__ Bm,
    float* __restrict__ C, const float* __restrict__ bias,
    int M, int N, int K, int doRelu)
{
    __shared__ __attribute__((aligned(16))) float As[BK][BM + 4];
    __shared__ __attribute__((aligned(16))) float Bs[BK][BN + 4];
    const int tid = threadIdx.x;
    const int tx = tid & 15, ty = tid >> 4;
    const int bm = blockIdx.y * BM, bn = blockIdx.x * BN;
    const int lr  = tid >> 1;           // 0..127 row within tile
    const int lc4 = (tid & 1) * 16;     // starting float col: 0 or 16
    const float* Aptr = A + (size_t)(bm + lr) * K + lc4;
    const float* Bptr = Bm + (size_t)(bn + lr) * K + lc4;
    float acc[8][8] = {};
    for (int k0 = 0; k0 < K; k0 += BK) {
        float4 av[4], bv4[4];
#pragma unroll
        for (int j = 0; j < 4; ++j) {
            av[j]  = *(const float4*)(Aptr + k0 + j * 4);
            bv4[j] = *(const float4*)(Bptr + k0 + j * 4);
        }
        __syncthreads();
#pragma unroll
        for (int j = 0; j < 4; ++j) {
            int col = lc4 + j * 4;
            As[col + 0][lr] = av[j].x;  As[col + 1][lr] = av[j].y;
            As[col + 2][lr] = av[j].z;  As[col + 3][lr] = av[j].w;
            Bs[col + 0][lr] = bv4[j].x; Bs[col + 1][lr] = bv4[j].y;
            Bs[col + 2][lr] = bv4[j].z; Bs[col + 3][lr] = bv4[j].w;
        }
        __syncthreads();
#pragma unroll
        for (int kk = 0; kk < BK; ++kk) {
            float a[8], bv[8];
            *(float4*)&a[0]  = *(const float4*)&As[kk][ty * 8];
            *(float4*)&a[4]  = *(const float4*)&As[kk][ty * 8 + 4];
            *(float4*)&bv[0] = *(const float4*)&Bs[kk][tx * 8];
            *(float4*)&bv[4] = *(const float4*)&Bs[kk][tx * 8 + 4];
#pragma unroll
            for (int i = 0; i < 8; ++i)
#pragma unroll
                for (int j = 0; j < 8; ++j)
                    acc[i][j] = fmaf(a[i], bv[j], acc[i][j]);
        }
    }
    float bloc[8];
#pragma unroll
    for (int j = 0; j < 8; ++j) bloc[j] = bias ? bias[bn + tx * 8 + j] : 0.f;
#pragma unroll
    for (int i = 0; i < 8; ++i) {
        int m = bm + ty * 8 + i;
        float* crow = C + (size_t)m * N + bn + tx * 8;
        float v[8];
#pragma unroll
        for (int j = 0; j < 8; ++j) {
            float t = acc[i][j] + bloc[j];
            v[j] = doRelu ? fmaxf(t, 0.f) : t;
        }
        *(float4*)(crow)     = make_float4(v[0], v[1], v[2], v[3]);
        *(float4*)(crow + 4) = make_float4(v[4], v[5], v[6], v[7]);
    }
}

__global__ __launch_bounds__(256) void k_topk_up(const float* __restrict__ big,
                                                 int* __restrict__ up_idx,
                                                 float* __restrict__ up_val) {
    __shared__ __attribute__((aligned(16))) float row[FUP];
    __shared__ unsigned hist[256];
    __shared__ int scratch[68];
    int b = blockIdx.x;
    const float4* s4 = (const float4*)(big + (size_t)b * FUP);
    float4* r4 = (float4*)row;
    for (int i = threadIdx.x; i < FUP / 4; i += 256) r4[i] = s4[i];
    __syncthreads();
    topk64_block(row, FUP, up_idx + b * 64, up_val + b * 64, hist, scratch);
}

// pd[fd,c] = W_enc_down[fd]·W_dec_upT[conn[fd,c]]  (0 on duplicate conn)
// fu-windowed for per-XCD L2 residency: grid (fd, window), window = slow dim
// so co-resident blocks share one 3 MB WduT window. Dot arithmetic is
// bit-identical to the round-2 version.
__global__ __launch_bounds__(256) void k_pd_win(const float* __restrict__ Wdn,
                                                const float* __restrict__ WduT,
                                                const int* __restrict__ conn,
                                                const int* __restrict__ mode_p,
                                                float* __restrict__ pd) {
    __shared__ float wrow[D_];
    __shared__ int crow[CONN];
    int fd = blockIdx.x;
    int wlo = blockIdx.y * PDW;
    int mode = *mode_p;
    const float* wsrc = Wdn + (size_t)fd * D_;
    for (int i = threadIdx.x; i < D_; i += 256) wrow[i] = wsrc[i];
    for (int i = threadIdx.x; i < CONN; i += 256)
        crow[i] = getconn(conn, (size_t)fd * CONN + i, mode);
    __syncthreads();
    int wave = threadIdx.x >> 6, lane = threadIdx.x & 63;
    for (int c = wave; c < CONN; c += 4) {
        int fu = crow[c];
        if ((unsigned)(fu - wlo) >= (unsigned)PDW) continue;  // wave-uniform
        bool dup = false;
        for (int q = lane; q < c; q += 64) dup |= (crow[q] == fu);
        unsigned long long anyDup = __ballot(dup);
        const float* wu = WduT + (size_t)fu * D_;
        float s = 0.f;
        for (int d = lane; d < D_; d += 64) s += wrow[d] * wu[d];
        for (int m = 32; m; m >>= 1) s += __shfl_xor(s, m);
        if (!lane) pd[(size_t)fd * CONN + c] = anyDup ? 0.f : s;
    }
}

__global__ void k_hist(const int* __restrict__ conn, const int* __restrict__ mode_p,
                       unsigned* __restrict__ counts, int total) {
    int mode = *mode_p;
    for (int e = blockIdx.x * blockDim.x + threadIdx.x; e < total;
         e += gridDim.x * blockDim.x)
        atomicAdd(&counts[getconn(conn, (size_t)e, mode)], 1u);
}

__global__ void k_scan(const unsigned* __restrict__ counts,
                       unsigned* __restrict__ offsets, unsigned* __restrict__ cursor) {
    __shared__ unsigned sums[256];
    int tid = threadIdx.x;
    const int CH = FUP / 256;   // 48
    unsigned local = 0;
    for (int i = 0; i < CH; ++i) local += counts[tid * CH + i];
    sums[tid] = local;
    __syncthreads();
    for (int off = 1; off < 256; off <<= 1) {
        unsigned v = 0;
        if (tid >= off) v = sums[tid - off];
        __syncthreads();
        sums[tid] += v;
        __syncthreads();
    }
    unsigned run = (tid == 0) ? 0u : sums[tid - 1];
    for (int i = 0; i < CH; ++i) {
        int idx = tid * CH + i;
        offsets[idx] = run;
        cursor[idx]  = run;
        run += counts[idx];
    }
    if (tid == 255) offsets[FUP] = run;
}

__global__ void k_scatter(const int* __restrict__ conn, const int* __restrict__ mode_p,
                          const float* __restrict__ pd, unsigned* __restrict__ cursor,
                          unsigned short* __restrict__ rev_fd, float* __restrict__ rev_w,
                          int total) {
    int mode = *mode_p;
    for (int e = blockIdx.x * blockDim.x + threadIdx.x; e < total;
         e += gridDim.x * blockDim.x) {
        int fu = getconn(conn, (size_t)e, mode);
        unsigned pos = atomicAdd(&cursor[fu], 1u);
        rev_fd[pos] = (unsigned short)(e >> 8);   // fd = e / CONN
        rev_w[pos]  = pd[e];
    }
}

// per-batch-row: contributions scatter + combine + top-64 of approx
__global__ __launch_bounds__(256) void k_down(
    const float* __restrict__ big /*approx0*/, const float* __restrict__ ln_scale,
    const float* __restrict__ c_in, const float* __restrict__ c_out,
    const int* __restrict__ up_idx, const float* __restrict__ up_val,
    const unsigned* __restrict__ offsets, const unsigned short* __restrict__ rev_fd,
    const float* __restrict__ rev_w, int* __restrict__ down_idx,
    float* __restrict__ down_val)
{
    __shared__ __attribute__((aligned(16))) float contrib[FDN];
    __shared__ unsigned hist[256];
    __shared__ int scratch[68];
    int b = blockIdx.x, tid = threadIdx.x;
    float4* c4 = (float4*)contrib;
    for (int i = tid; i < FDN / 4; i += 256) c4[i] = make_float4(0.f, 0.f, 0.f, 0.f);
    __syncthreads();
    for (int j = 0; j < KTOP; ++j) {
        int fu = up_idx[b * 64 + j];
        float v = up_val[b * 64 + j];
        unsigned s = offsets[fu], e = offsets[fu + 1];
        for (unsigned t = s + tid; t < e; t += 256)
            atomicAdd(&contrib[rev_fd[t]], v * rev_w[t]);
    }
    __syncthreads();
    float ls = ln_scale[b];
    const float* ap = big + (size_t)b * FDN;
    for (int i = tid; i < FDN; i += 256)
        contrib[i] = (ap[i] + contrib[i] + c_in[i]) / ls + c_out[i];
    __syncthreads();
    topk64_block(contrib, FDN, down_idx + b * 64, down_val + b * 64, hist, scratch);
}

__global__ __launch_bounds__(256) void k_decode(
    const int* __restrict__ down_idx, const float* __restrict__ down_val,
    const float* __restrict__ WddT, const float* __restrict__ b_dec_down,
    float* __restrict__ out)
{
    __shared__ int fidx[64];
    __shared__ float fval[64];
    int b = blockIdx.x, tid = threadIdx.x;
    if (tid < 64) { fidx[tid] = down_idx[b * 64 + tid]; fval[tid] = down_val[b * 64 + tid]; }
    __syncthreads();
    float a0 = b_dec_down[tid], a1 = b_dec_down[tid + 256], a2 = b_dec_down[tid + 512];
    for (int j = 0; j < 64; ++j) {
        const float* r = WddT + (size_t)fidx[j] * D_;
        float v = fval[j];
        a0 += v * r[tid];
        a1 += v * r[tid + 256];
        a2 += v * r[tid + 512];
    }
    float* o = out + (size_t)b * D_;
    o[tid] = a0; o[tid + 256] = a1; o[tid + 512] = a2;
}

// ---------------------------------------------------------------- launch

extern "C" void kernel_launch(void* const* d_in, const int* in_sizes, int n_in,
                              void* d_out, int out_size, void* d_ws, size_t ws_size,
                              hipStream_t stream)
{
    const float* initial_acts = (const float*)d_in[0];
    const float* x_up         = (const float*)d_in[1];
    const float* ln_scale     = (const float*)d_in[2];
    const float* W_enc_up     = (const float*)d_in[3];
    const float* b_enc_up     = (const float*)d_in[4];
    const float* b_dec_up     = (const float*)d_in[5];
    const float* W_dec_up     = (const float*)d_in[6];
    const float* W_enc_down   = (const float*)d_in[7];
    const float* b_enc_down   = (const float*)d_in[8];
    const float* b_dec_down   = (const float*)d_in[9];
    const float* W_dec_down   = (const float*)d_in[10];
    const int*   conn         = (const int*)d_in[11];
    float* out = (float*)d_out;

    // ---- workspace layout (total ~111.5 MB; unchanged from round 2) ----
    char* w = (char*)d_ws;
    float*          big      = (float*)(w);                 // 50,331,648 B (CHUNK x FUP)
    float*          pd       = big;                         // overlap: dead before GEMM2 chunks
    float*          Wt       = (float*)(w + 50331648);      // 37,748,736 B (WduT then WddT)
    float*          rev_w    = (float*)(w + 88080384);      // 12,582,912 B
    unsigned short* rev_fd   = (unsigned short*)(w + 100663296); // 6,291,456 B
    int*            up_idx   = (int*)  (w + 106954752);     // 1 MiB
    float*          up_val   = (float*)(w + 108003328);     // 1 MiB
    int*            down_idx = (int*)  (w + 109051904);     // 1 MiB
    float*          down_val = (float*)(w + 110100480);     // 1 MiB
    unsigned*       offsets  = (unsigned*)(w + 111149056);  // 64 KiB (12289 used)
    unsigned*       cursor   = (unsigned*)(w + 111214592);  // 64 KiB
    unsigned*       counts   = (unsigned*)(w + 111280128);  // 64 KiB
    float*          bias_up  = (float*)(w + 111345664);     // 48 KiB
    float*          c_in     = (float*)(w + 111394816);     // 48 KiB
    float*          c_out    = (float*)(w + 111443968);     // 48 KiB
    int*            mode_p   = (int*)  (w + 111493120);

    const int total_conn = FDN * CONN;
    dim3 tb(32, 8);

    k_detect<<<1, 64, 0, stream>>>(conn, mode_p);
    k_transpose<<<dim3(FUP / 32, D_ / 32), tb, 0, stream>>>(W_dec_up, Wt, D_, FUP);
    k_precompute<<<FUP / 4, 256, 0, stream>>>(W_enc_up, W_enc_down, b_enc_up, b_enc_down,
                                              b_dec_up, b_dec_down, bias_up, c_in, c_out);
    // phase 1: pre_up = relu(x_up @ W_enc_up^T + bias_up), then top-64, per chunk
    for (int c = 0; c < NCH; ++c) {
        k_gemm_nt<<<dim3(FUP / BN, CHUNK / BM), 256, 0, stream>>>(
            x_up + (size_t)c * CHUNK * D_, W_enc_up, big, bias_up, CHUNK, FUP, D_, 1);
        k_topk_up<<<CHUNK, 256, 0, stream>>>(big, up_idx + (size_t)c * CHUNK * 64,
                                             up_val + (size_t)c * CHUNK * 64);
    }
    // pair dots into pd (overlaps big; pre_up chunks are dead), fu-windowed
    k_pd_win<<<dim3(FDN, NPW), 256, 0, stream>>>(W_enc_down, Wt, conn, mode_p, pd);
    k_zero<<<48, 256, 0, stream>>>(counts, FUP);
    k_hist<<<4096, 256, 0, stream>>>(conn, mode_p, counts, total_conn);
    k_scan<<<1, 256, 0, stream>>>(counts, offsets, cursor);
    k_scatter<<<4096, 256, 0, stream>>>(conn, mode_p, pd, cursor, rev_fd, rev_w, total_conn);
    // WddT (WduT dead after k_pd_win)
    k_transpose<<<dim3(FDN / 32, D_ / 32), tb, 0, stream>>>(W_dec_down, Wt, D_, FDN);
    // phase 2: approx0 = initial_acts @ W_enc_down^T, combine + top-64, per chunk
    for (int c = 0; c < NCH; ++c) {
        k_gemm_nt<<<dim3(FDN / BN, CHUNK / BM), 256, 0, stream>>>(
            initial_acts + (size_t)c * CHUNK * D_, W_enc_down, big, nullptr,
            CHUNK, FDN, D_, 0);
        k_down<<<CHUNK, 256, 0, stream>>>(big, ln_scale + (size_t)c * CHUNK, c_in, c_out,
                                          up_idx + (size_t)c * CHUNK * 64,
                                          up_val + (size_t)c * CHUNK * 64,
                                          offsets, rev_fd, rev_w,
                                          down_idx + (size_t)c * CHUNK * 64,
                                          down_val + (size_t)c * CHUNK * 64);
    }
    k_decode<<<B_, 256, 0, stream>>>(down_idx, down_val, Wt, b_dec_down, out);
}

// Round 4
// 4660.235 us; speedup vs baseline: 1.2644x; 1.2430x over previous
//
#include <hip/hip_runtime.h>
#include <stdint.h>

#define B_    4096
#define D_    768
#define FUP   12288
#define FDN   12288
#define CONN  256
#define KTOP  64
#define CHUNK 1024
#define NCH   (B_ / CHUNK)
#define PDW   1024            // k_pd fu-window (3 MB fp32: fits 4 MB per-XCD L2)
#define NPW   (FUP / PDW)     // 12 windows (+1 dup bucket)

// ---------------------------------------------------------------- utilities

__device__ __forceinline__ unsigned fkey(float x) {
    unsigned u = __float_as_uint(x);
    return (u & 0x80000000u) ? ~u : (u | 0x80000000u);
}

// Block-wide top-64 select over vals[0..n) (LDS resident), exact jax
// tie-breaking (lowest index among equals at the threshold).
__device__ void topk64_block(const float* vals, int n, int* gidx, float* gval,
                             unsigned* hist, int* scratch)
{
    const int tid = threadIdx.x;
    if (tid == 0) { scratch[0] = KTOP; scratch[1] = 0; scratch[2] = 0; scratch[3] = 0; }
    for (int l = 24; l >= 0; l -= 8) {
        hist[tid] = 0;
        __syncthreads();
        unsigned prefix = (unsigned)scratch[1];
        unsigned hm = (l == 24) ? 0u : (0xFFFFFFFFu << (l + 8));
        for (int i = tid; i < n; i += 256) {
            unsigned key = fkey(vals[i]);
            if ((key & hm) == (prefix & hm)) atomicAdd(&hist[(key >> l) & 255], 1u);
        }
        __syncthreads();
        if (tid == 0) {
            int need = scratch[0];
            unsigned acc = 0;
            for (int b2 = 255; b2 >= 0; --b2) {
                unsigned h = hist[b2];
                if (acc + h >= (unsigned)need) {
                    scratch[1] = (int)(prefix | ((unsigned)b2 << l));
                    scratch[0] = need - (int)acc;
                    break;
                }
                acc += h;
            }
        }
        __syncthreads();
    }
    unsigned thresh = (unsigned)scratch[1];
    for (int i = tid; i < n; i += 256) {
        float v = vals[i];
        unsigned key = fkey(v);
        if (key > thresh) {
            int p = atomicAdd(&scratch[2], 1);
            gidx[p] = i; gval[p] = v;
        } else if (key == thresh) {
            int p = atomicAdd(&scratch[3], 1);
            if (p < 64) scratch[4 + p] = i;
        }
    }
    __syncthreads();
    if (tid == 0) {
        int cnt = scratch[2];
        int ne  = KTOP - cnt;
        int ec  = scratch[3] < 64 ? scratch[3] : 64;
        for (int a2 = 0; a2 < ne; ++a2) {
            int best = 0x7fffffff, bi = -1;
            for (int q = 0; q < ec; ++q) {
                int id = scratch[4 + q];
                if (id >= 0 && id < best) { best = id; bi = q; }
            }
            if (bi >= 0) {
                scratch[4 + bi] = -1;
                gidx[cnt + a2] = best; gval[cnt + a2] = vals[best];
            }
        }
    }
    __syncthreads();
}

// ---------------------------------------------------------------- kernels

__global__ void k_detect(const int* __restrict__ conn, int* mode) {
    if (blockIdx.x == 0 && threadIdx.x == 0) {
        int z = 1;
        for (int i = 1; i < 128; i += 2) z &= (conn[i] == 0);
        *mode = z;
    }
}

__device__ __forceinline__ int getconn(const int* c, size_t e, int mode) {
    return mode ? c[2 * e] : c[e];
}

__global__ void k_zero(unsigned* __restrict__ p, int n) {
    for (int i = blockIdx.x * blockDim.x + threadIdx.x; i < n;
         i += gridDim.x * blockDim.x)
        p[i] = 0u;
}

// in[R][Cc] -> out[Cc][R]
__global__ void k_transpose(const float* __restrict__ in, float* __restrict__ out,
                            int R, int Cc) {
    __shared__ float t[32][33];
    int x = blockIdx.x * 32 + threadIdx.x;
    int yb = blockIdx.y * 32;
    for (int j = threadIdx.y; j < 32; j += 8)
        t[j][threadIdx.x] = in[(size_t)(yb + j) * Cc + x];
    __syncthreads();
    int xo  = yb + threadIdx.x;
    int yb2 = blockIdx.x * 32;
    for (int j = threadIdx.y; j < 32; j += 8)
        out[(size_t)(yb2 + j) * R + xo] = t[threadIdx.x][j];
}

__global__ void k_precompute(const float* __restrict__ Wup, const float* __restrict__ Wdn,
                             const float* __restrict__ b_enc_up, const float* __restrict__ b_enc_down,
                             const float* __restrict__ b_dec_up, const float* __restrict__ b_dec_down,
                             float* __restrict__ bias_up, float* __restrict__ c_in,
                             float* __restrict__ c_out) {
    int wave = threadIdx.x >> 6, lane = threadIdx.x & 63;
    int f = blockIdx.x * 4 + wave;
    if (f >= FUP) return;
    const float* ru = Wup + (size_t)f * D_;
    const float* rd = Wdn + (size_t)f * D_;
    float s1 = 0.f, s2 = 0.f, s3 = 0.f;
    for (int d = lane; d < D_; d += 64) {
        float bu = b_dec_up[d], bd = b_dec_down[d];
        s1 += ru[d] * bu;
        float w = rd[d];
        s2 += w * bu;
        s3 += w * bd;
    }
    for (int m = 32; m; m >>= 1) {
        s1 += __shfl_xor(s1, m);
        s2 += __shfl_xor(s2, m);
        s3 += __shfl_xor(s3, m);
    }
    if (!lane) {
        bias_up[f] = b_enc_up[f] - s1;
        c_in[f]  = s2;
        c_out[f] = b_enc_down[f] - s3;
    }
}

// C[M,N] = A[M,K] @ B[N,K]^T (+bias) (+relu).  128x128 tile, 8x8 microtile.
#define BM 128
#define BN 128
#define BK 32
__global__ __launch_bounds__(256, 2) void k_gemm_nt(
    const float* __restrict__ A, const float* __restrict__ Bm,
    float* __restrict__ C, const float* __restrict__ bias,
    int M, int N, int K, int doRelu)
{
    __shared__ __attribute__((aligned(16))) float As[BK][BM + 4];
    __shared__ __attribute__((aligned(16))) float Bs[BK][BN + 4];
    const int tid = threadIdx.x;
    const int tx = tid & 15, ty = tid >> 4;
    const int bm = blockIdx.y * BM, bn = blockIdx.x * BN;
    const int lr  = tid >> 1;           // 0..127 row within tile
    const int lc4 = (tid & 1) * 16;     // starting float col: 0 or 16
    const float* Aptr = A + (size_t)(bm + lr) * K + lc4;
    const float* Bptr = Bm + (size_t)(bn + lr) * K + lc4;
    float acc[8][8] = {};
    for (int k0 = 0; k0 < K; k0 += BK) {
        float4 av[4], bv4[4];
#pragma unroll
        for (int j = 0; j < 4; ++j) {
            av[j]  = *(const float4*)(Aptr + k0 + j * 4);
            bv4[j] = *(const float4*)(Bptr + k0 + j * 4);
        }
        __syncthreads();
#pragma unroll
        for (int j = 0; j < 4; ++j) {
            int col = lc4 + j * 4;
            As[col + 0][lr] = av[j].x;  As[col + 1][lr] = av[j].y;
            As[col + 2][lr] = av[j].z;  As[col + 3][lr] = av[j].w;
            Bs[col + 0][lr] = bv4[j].x; Bs[col + 1][lr] = bv4[j].y;
            Bs[col + 2][lr] = bv4[j].z; Bs[col + 3][lr] = bv4[j].w;
        }
        __syncthreads();
#pragma unroll
        for (int kk = 0; kk < BK; ++kk) {
            float a[8], bv[8];
            *(float4*)&a[0]  = *(const float4*)&As[kk][ty * 8];
            *(float4*)&a[4]  = *(const float4*)&As[kk][ty * 8 + 4];
            *(float4*)&bv[0] = *(const float4*)&Bs[kk][tx * 8];
            *(float4*)&bv[4] = *(const float4*)&Bs[kk][tx * 8 + 4];
#pragma unroll
            for (int i = 0; i < 8; ++i)
#pragma unroll
                for (int j = 0; j < 8; ++j)
                    acc[i][j] = fmaf(a[i], bv[j], acc[i][j]);
        }
    }
    float bloc[8];
#pragma unroll
    for (int j = 0; j < 8; ++j) bloc[j] = bias ? bias[bn + tx * 8 + j] : 0.f;
#pragma unroll
    for (int i = 0; i < 8; ++i) {
        int m = bm + ty * 8 + i;
        float* crow = C + (size_t)m * N + bn + tx * 8;
        float v[8];
#pragma unroll
        for (int j = 0; j < 8; ++j) {
            float t = acc[i][j] + bloc[j];
            v[j] = doRelu ? fmaxf(t, 0.f) : t;
        }
        *(float4*)(crow)     = make_float4(v[0], v[1], v[2], v[3]);
        *(float4*)(crow + 4) = make_float4(v[4], v[5], v[6], v[7]);
    }
}

__global__ __launch_bounds__(256) void k_topk_up(const float* __restrict__ big,
                                                 int* __restrict__ up_idx,
                                                 float* __restrict__ up_val) {
    __shared__ __attribute__((aligned(16))) float row[FUP];
    __shared__ unsigned hist[256];
    __shared__ int scratch[68];
    int b = blockIdx.x;
    const float4* s4 = (const float4*)(big + (size_t)b * FUP);
    float4* r4 = (float4*)row;
    for (int i = threadIdx.x; i < FUP / 4; i += 256) r4[i] = s4[i];
    __syncthreads();
    topk64_block(row, FUP, up_idx + b * 64, up_val + b * 64, hist, scratch);
}

// Counting-sort each fd's 256 connections into NPW fu-window buckets plus a
// dup bucket (index NPW). Output: ent_fu/ent_c (window-sorted per fd) and
// per-fd bucket offsets woff[fd][NPW+2] (last = 256).
__global__ __launch_bounds__(256) void k_sortwin(
    const int* __restrict__ conn, const int* __restrict__ mode_p,
    unsigned short* __restrict__ ent_fu, unsigned char* __restrict__ ent_c,
    unsigned short* __restrict__ woff)
{
    __shared__ int crow[CONN];
    __shared__ int cnt[NPW + 1];
    __shared__ int base[NPW + 1];
    __shared__ int cur[NPW + 1];
    int fd = blockIdx.x, tid = threadIdx.x;
    int mode = *mode_p;
    crow[tid] = getconn(conn, (size_t)fd * CONN + tid, mode);
    if (tid <= NPW) cnt[tid] = 0;
    __syncthreads();
    int fu = crow[tid];
    bool dup = false;
    for (int q = 0; q < tid; ++q) dup |= (crow[q] == fu);
    int win = dup ? NPW : (fu / PDW);
    atomicAdd(&cnt[win], 1);
    __syncthreads();
    if (tid == 0) {
        int run = 0;
        for (int i = 0; i <= NPW; ++i) { base[i] = run; run += cnt[i]; }
    }
    __syncthreads();
    if (tid <= NPW) {
        woff[fd * (NPW + 2) + tid] = (unsigned short)base[tid];
        cur[tid] = base[tid];
    }
    if (tid == 0) woff[fd * (NPW + 2) + NPW + 1] = (unsigned short)CONN;
    __syncthreads();
    int pos = atomicAdd(&cur[win], 1);
    ent_fu[(size_t)fd * CONN + pos] = (unsigned short)fu;
    ent_c[(size_t)fd * CONN + pos]  = (unsigned char)tid;
}

// pd[fd,c] = W_enc_down[fd]·W_dec_upT[fu]  via window-sorted entry lists.
// Grid (fd, window); window is the slow dim so co-resident blocks share one
// 3 MB WduT window (L2-resident). 4 dots per wave (16 lanes each).
__global__ __launch_bounds__(256) void k_pd2(
    const float* __restrict__ Wdn, const float* __restrict__ WduT,
    const unsigned short* __restrict__ ent_fu, const unsigned char* __restrict__ ent_c,
    const unsigned short* __restrict__ woff, float* __restrict__ pd)
{
    __shared__ __attribute__((aligned(16))) float wrow[D_];
    int fd = blockIdx.x, win = blockIdx.y, tid = threadIdx.x;
    int s = woff[fd * (NPW + 2) + win];
    int e = woff[fd * (NPW + 2) + win + 1];
    if (win == NPW) {           // dup bucket: masked entries contribute 0
        for (int t = s + tid; t < e; t += 256)
            pd[(size_t)fd * CONN + ent_c[(size_t)fd * CONN + t]] = 0.f;
        return;
    }
    if (s == e) return;
    const float4* wsrc = (const float4*)(Wdn + (size_t)fd * D_);
    for (int i = tid; i < D_ / 4; i += 256) ((float4*)wrow)[i] = wsrc[i];
    __syncthreads();
    const int wave = tid >> 6, lane = tid & 63;
    const int grp = lane >> 4, gi = lane & 15;
    float4 wr[12];
#pragma unroll
    for (int j = 0; j < 12; ++j)
        wr[j] = *(const float4*)&wrow[gi * 4 + j * 64];
    for (int q = s + wave * 4; q < e; q += 16) {
        int idx = q + grp;
        bool act = idx < e;
        int idxc = act ? idx : (e - 1);
        int fu = ent_fu[(size_t)fd * CONN + idxc];
        const float* wu = WduT + (size_t)fu * D_;
        float sacc = 0.f;
#pragma unroll
        for (int j = 0; j < 12; ++j) {
            float4 u = *(const float4*)&wu[gi * 4 + j * 64];
            sacc = fmaf(u.x, wr[j].x, sacc);
            sacc = fmaf(u.y, wr[j].y, sacc);
            sacc = fmaf(u.z, wr[j].z, sacc);
            sacc = fmaf(u.w, wr[j].w, sacc);
        }
#pragma unroll
        for (int m = 1; m < 16; m <<= 1) sacc += __shfl_xor(sacc, m);
        if (act && gi == 0)
            pd[(size_t)fd * CONN + ent_c[(size_t)fd * CONN + idx]] = sacc;
    }
}

__global__ void k_hist(const int* __restrict__ conn, const int* __restrict__ mode_p,
                       unsigned* __restrict__ counts, int total) {
    int mode = *mode_p;
    for (int e = blockIdx.x * blockDim.x + threadIdx.x; e < total;
         e += gridDim.x * blockDim.x)
        atomicAdd(&counts[getconn(conn, (size_t)e, mode)], 1u);
}

__global__ void k_scan(const unsigned* __restrict__ counts,
                       unsigned* __restrict__ offsets, unsigned* __restrict__ cursor) {
    __shared__ unsigned sums[256];
    int tid = threadIdx.x;
    const int CH = FUP / 256;   // 48
    unsigned local = 0;
    for (int i = 0; i < CH; ++i) local += counts[tid * CH + i];
    sums[tid] = local;
    __syncthreads();
    for (int off = 1; off < 256; off <<= 1) {
        unsigned v = 0;
        if (tid >= off) v = sums[tid - off];
        __syncthreads();
        sums[tid] += v;
        __syncthreads();
    }
    unsigned run = (tid == 0) ? 0u : sums[tid - 1];
    for (int i = 0; i < CH; ++i) {
        int idx = tid * CH + i;
        offsets[idx] = run;
        cursor[idx]  = run;
        run += counts[idx];
    }
    if (tid == 255) offsets[FUP] = run;
}

__global__ void k_scatter(const int* __restrict__ conn, const int* __restrict__ mode_p,
                          const float* __restrict__ pd, unsigned* __restrict__ cursor,
                          unsigned short* __restrict__ rev_fd, float* __restrict__ rev_w,
                          int total) {
    int mode = *mode_p;
    for (int e = blockIdx.x * blockDim.x + threadIdx.x; e < total;
         e += gridDim.x * blockDim.x) {
        int fu = getconn(conn, (size_t)e, mode);
        unsigned pos = atomicAdd(&cursor[fu], 1u);
        rev_fd[pos] = (unsigned short)(e >> 8);   // fd = e / CONN
        rev_w[pos]  = pd[e];
    }
}

// per-batch-row: contributions scatter + combine + top-64 of approx
__global__ __launch_bounds__(256) void k_down(
    const float* __restrict__ big /*approx0*/, const float* __restrict__ ln_scale,
    const float* __restrict__ c_in, const float* __restrict__ c_out,
    const int* __restrict__ up_idx, const float* __restrict__ up_val,
    const unsigned* __restrict__ offsets, const unsigned short* __restrict__ rev_fd,
    const float* __restrict__ rev_w, int* __restrict__ down_idx,
    float* __restrict__ down_val)
{
    __shared__ __attribute__((aligned(16))) float contrib[FDN];
    __shared__ unsigned hist[256];
    __shared__ int scratch[68];
    int b = blockIdx.x, tid = threadIdx.x;
    float4* c4 = (float4*)contrib;
    for (int i = tid; i < FDN / 4; i += 256) c4[i] = make_float4(0.f, 0.f, 0.f, 0.f);
    __syncthreads();
    for (int j = 0; j < KTOP; ++j) {
        int fu = up_idx[b * 64 + j];
        float v = up_val[b * 64 + j];
        unsigned s = offsets[fu], e = offsets[fu + 1];
        for (unsigned t = s + tid; t < e; t += 256)
            atomicAdd(&contrib[rev_fd[t]], v * rev_w[t]);
    }
    __syncthreads();
    float ls = ln_scale[b];
    const float* ap = big + (size_t)b * FDN;
    for (int i = tid; i < FDN; i += 256)
        contrib[i] = (ap[i] + contrib[i] + c_in[i]) / ls + c_out[i];
    __syncthreads();
    topk64_block(contrib, FDN, down_idx + b * 64, down_val + b * 64, hist, scratch);
}

__global__ __launch_bounds__(256) void k_decode(
    const int* __restrict__ down_idx, const float* __restrict__ down_val,
    const float* __restrict__ WddT, const float* __restrict__ b_dec_down,
    float* __restrict__ out)
{
    __shared__ int fidx[64];
    __shared__ float fval[64];
    int b = blockIdx.x, tid = threadIdx.x;
    if (tid < 64) { fidx[tid] = down_idx[b * 64 + tid]; fval[tid] = down_val[b * 64 + tid]; }
    __syncthreads();
    float a0 = b_dec_down[tid], a1 = b_dec_down[tid + 256], a2 = b_dec_down[tid + 512];
    for (int j = 0; j < 64; ++j) {
        const float* r = WddT + (size_t)fidx[j] * D_;
        float v = fval[j];
        a0 += v * r[tid];
        a1 += v * r[tid + 256];
        a2 += v * r[tid + 512];
    }
    float* o = out + (size_t)b * D_;
    o[tid] = a0; o[tid + 256] = a1; o[tid + 512] = a2;
}

// ---------------------------------------------------------------- launch

extern "C" void kernel_launch(void* const* d_in, const int* in_sizes, int n_in,
                              void* d_out, int out_size, void* d_ws, size_t ws_size,
                              hipStream_t stream)
{
    const float* initial_acts = (const float*)d_in[0];
    const float* x_up         = (const float*)d_in[1];
    const float* ln_scale     = (const float*)d_in[2];
    const float* W_enc_up     = (const float*)d_in[3];
    const float* b_enc_up     = (const float*)d_in[4];
    const float* b_dec_up     = (const float*)d_in[5];
    const float* W_dec_up     = (const float*)d_in[6];
    const float* W_enc_down   = (const float*)d_in[7];
    const float* b_enc_down   = (const float*)d_in[8];
    const float* b_dec_down   = (const float*)d_in[9];
    const float* W_dec_down   = (const float*)d_in[10];
    const int*   conn         = (const int*)d_in[11];
    float* out = (float*)d_out;

    // ---- workspace layout (total ~121.3 MB; stay under 128 MiB) ----
    char* w = (char*)d_ws;
    float*          big      = (float*)(w);                 // 50,331,648 B (CHUNK x FUP)
    float*          pd       = big;                         // overlap: dead before GEMM2 chunks
    float*          Wt       = (float*)(w + 50331648);      // 37,748,736 B (WduT then WddT)
    float*          rev_w    = (float*)(w + 88080384);      // 12,582,912 B
    unsigned short* rev_fd   = (unsigned short*)(w + 100663296); // 6,291,456 B
    int*            up_idx   = (int*)  (w + 106954752);     // 1 MiB
    float*          up_val   = (float*)(w + 108003328);     // 1 MiB
    int*            down_idx = (int*)  (w + 109051904);     // 1 MiB
    float*          down_val = (float*)(w + 110100480);     // 1 MiB
    unsigned*       offsets  = (unsigned*)(w + 111149056);  // 64 KiB (12289 used)
    unsigned*       cursor   = (unsigned*)(w + 111214592);  // 64 KiB
    unsigned*       counts   = (unsigned*)(w + 111280128);  // 64 KiB
    float*          bias_up  = (float*)(w + 111345664);     // 48 KiB
    float*          c_in     = (float*)(w + 111394816);     // 48 KiB
    float*          c_out    = (float*)(w + 111443968);     // 48 KiB
    int*            mode_p   = (int*)  (w + 111493120);     // 4 B
    unsigned short* ent_fu   = (unsigned short*)(w + 111546368); // 6,291,456 B
    unsigned char*  ent_c    = (unsigned char*) (w + 117837824); // 3,145,728 B
    unsigned short* woff     = (unsigned short*)(w + 120983552); // 344,064 B
    // ends at 121,327,616 B

    const int total_conn = FDN * CONN;
    dim3 tb(32, 8);

    k_detect<<<1, 64, 0, stream>>>(conn, mode_p);
    k_sortwin<<<FDN, 256, 0, stream>>>(conn, mode_p, ent_fu, ent_c, woff);
    k_transpose<<<dim3(FUP / 32, D_ / 32), tb, 0, stream>>>(W_dec_up, Wt, D_, FUP);
    k_precompute<<<FUP / 4, 256, 0, stream>>>(W_enc_up, W_enc_down, b_enc_up, b_enc_down,
                                              b_dec_up, b_dec_down, bias_up, c_in, c_out);
    // phase 1: pre_up = relu(x_up @ W_enc_up^T + bias_up), then top-64, per chunk
    for (int c = 0; c < NCH; ++c) {
        k_gemm_nt<<<dim3(FUP / BN, CHUNK / BM), 256, 0, stream>>>(
            x_up + (size_t)c * CHUNK * D_, W_enc_up, big, bias_up, CHUNK, FUP, D_, 1);
        k_topk_up<<<CHUNK, 256, 0, stream>>>(big, up_idx + (size_t)c * CHUNK * 64,
                                             up_val + (size_t)c * CHUNK * 64);
    }
    // pair dots into pd (overlaps big; pre_up chunks are dead), sorted windows
    k_pd2<<<dim3(FDN, NPW + 1), 256, 0, stream>>>(W_enc_down, Wt, ent_fu, ent_c, woff, pd);
    k_zero<<<48, 256, 0, stream>>>(counts, FUP);
    k_hist<<<4096, 256, 0, stream>>>(conn, mode_p, counts, total_conn);
    k_scan<<<1, 256, 0, stream>>>(counts, offsets, cursor);
    k_scatter<<<4096, 256, 0, stream>>>(conn, mode_p, pd, cursor, rev_fd, rev_w, total_conn);
    // WddT (WduT dead after k_pd2)
    k_transpose<<<dim3(FDN / 32, D_ / 32), tb, 0, stream>>>(W_dec_down, Wt, D_, FDN);
    // phase 2: approx0 = initial_acts @ W_enc_down^T, combine + top-64, per chunk
    for (int c = 0; c < NCH; ++c) {
        k_gemm_nt<<<dim3(FDN / BN, CHUNK / BM), 256, 0, stream>>>(
            initial_acts + (size_t)c * CHUNK * D_, W_enc_down, big, nullptr,
            CHUNK, FDN, D_, 0);
        k_down<<<CHUNK, 256, 0, stream>>>(big, ln_scale + (size_t)c * CHUNK, c_in, c_out,
                                          up_idx + (size_t)c * CHUNK * 64,
                                          up_val + (size_t)c * CHUNK * 64,
                                          offsets, rev_fd, rev_w,
                                          down_idx + (size_t)c * CHUNK * 64,
                                          down_val + (size_t)c * CHUNK * 64);
    }
    k_decode<<<B_, 256, 0, stream>>>(down_idx, down_val, Wt, b_dec_down, out);
}